// Round 3
// baseline (384.106 us; speedup 1.0000x reference)
//
#include <hip/hip_runtime.h>
#include <stdint.h>

// ---- problem constants ----
constexpr int Hh = 512, Ww = 512;     // pseudo image dims
constexpr int C  = 32;                // channels
constexpr int B  = 2;
constexpr int NL = 50000;
constexpr int NR = 20000;
constexpr float EPS = 1e-5f;
constexpr float SCALE = 0.25f;        // 1/sqrt(16)

// combined-constant block layout (float offsets) in ws
constexpr int CB_MATS = 0;        // 6 x 1024  (Mq1,Mk1,Mv1,Mq2,Mk2,Mv2)
constexpr int CB_CVEC = 6144;     // 6 x 32    (cq1,ck1,cv1,cq2,ck2,cv2)
constexpr int CB_PE1  = 6336;     // 9 x 32    projected pos-enc, branch 1
constexpr int CB_PE2  = 6624;     // 9 x 32    branch 2
constexpr int CB_INV  = 6912;     // kinv1,vinv1,kinv2,vinv2 (4 x 32)
constexpr int CB_TOT  = 7040;

// 3x3 INDEX_SHIFT order from reference
__device__ __constant__ int DX9[9] = {0,-1,1,0,-1,1,0,-1,1};
__device__ __constant__ int DY9[9] = {0,0,0,1,1,1,-1,-1,-1};

// ---------- build dense coord->pillar grid (grid pre-memset to -1) ----------
__global__ void build_grid_k(const int* __restrict__ coors, int n, int* __restrict__ grid) {
    int b = blockIdx.y;
    int i = blockIdx.x * blockDim.x + threadIdx.x;
    if (i >= n) return;
    int x = coors[((size_t)b * n + i) * 2 + 0];
    int y = coors[((size_t)b * n + i) * 2 + 1];
    grid[(size_t)b * Hh * Ww + x * Ww + y] = i;
}

// ---------- combine in-proj with per-branch linear: M = A(sec) @ W ----------
__global__ void combine_mats_k(const float* __restrict__ a1w, const float* __restrict__ a2w,
                               const float* __restrict__ q1w, const float* __restrict__ k1w,
                               const float* __restrict__ v1w, const float* __restrict__ q2w,
                               const float* __restrict__ k2w, const float* __restrict__ v2w,
                               float* __restrict__ cb) {
    int m = blockIdx.x;           // 0..5
    int t = threadIdx.x;          // 0..1023
    const float* A = (m < 3 ? a1w : a2w) + (m % 3) * C * C;  // (96,32) section rows
    const float* Wm;
    switch (m) { case 0: Wm=q1w; break; case 1: Wm=k1w; break; case 2: Wm=v1w; break;
                 case 3: Wm=q2w; break; case 4: Wm=k2w; break; default: Wm=v2w; }
    int r = t >> 5, d = t & 31;
    float s = 0.f;
    #pragma unroll
    for (int c = 0; c < C; ++c) s += A[r * C + c] * Wm[c * C + d];
    cb[CB_MATS + m * 1024 + r * C + d] = s;
}

// ---------- combined bias vectors, projected pos-enc, invalid-slot biases ----------
__global__ void combine_vecs_k(const float* __restrict__ a1w, const float* __restrict__ a1b,
                               const float* __restrict__ a2w, const float* __restrict__ a2b,
                               const float* __restrict__ q1b, const float* __restrict__ k1b,
                               const float* __restrict__ v1b, const float* __restrict__ q2b,
                               const float* __restrict__ k2b, const float* __restrict__ v2b,
                               const float* __restrict__ posw, const float* __restrict__ posb,
                               float* __restrict__ cb) {
    int t = threadIdx.x;
    if (t < 192) {                                   // c_m = A_m @ b_m + a_b section
        int m = t / 32, r = t & 31;
        const float* A  = (m < 3 ? a1w : a2w) + (m % 3) * C * C;
        const float* ab = (m < 3 ? a1b : a2b) + (m % 3) * C;
        const float* bv = (m == 0 ? q1b : m == 1 ? k1b : m == 2 ? v1b
                         : m == 3 ? q2b : m == 4 ? k2b : v2b);
        float s = ab[r];
        #pragma unroll
        for (int c = 0; c < C; ++c) s += A[r * C + c] * bv[c];
        cb[CB_CVEC + m * 32 + r] = s;
    } else if (t < 480) {                            // pe9v1 = A1v @ pe9[j]
        int u = t - 192; int j = u >> 5, r = u & 31;
        const float* A = a1w + 2 * C * C;
        float sx = (float)DX9[j], sy = (float)DY9[j];
        float s = 0.f;
        #pragma unroll
        for (int c = 0; c < C; ++c) {
            float pe = posw[c * 2 + 0] * sx + posw[c * 2 + 1] * sy + posb[c];
            s += A[r * C + c] * pe;
        }
        cb[CB_PE1 + j * 32 + r] = s;
    } else if (t < 768) {                            // pe9v2 = A2v @ pe9[j]
        int u = t - 480; int j = u >> 5, r = u & 31;
        const float* A = a2w + 2 * C * C;
        float sx = (float)DX9[j], sy = (float)DY9[j];
        float s = 0.f;
        #pragma unroll
        for (int c = 0; c < C; ++c) {
            float pe = posw[c * 2 + 0] * sx + posw[c * 2 + 1] * sy + posb[c];
            s += A[r * C + c] * pe;
        }
        cb[CB_PE2 + j * 32 + r] = s;
    } else if (t < 896) {                            // invalid-slot biases (in_proj k/v bias)
        int u = t - 768; int m = u >> 5, r = u & 31;
        cb[CB_INV + u] = (m == 0 ? a1b[32 + r] : m == 1 ? a1b[64 + r]
                        : m == 2 ? a2b[32 + r] : a2b[64 + r]);
    }
}

// ---------- LayerNorm + 3 fused 32x32 matvecs per pillar ----------
__global__ void ln_proj_k(const float* __restrict__ feats, int n,
                          const float* __restrict__ lnw, const float* __restrict__ lnb,
                          const float* __restrict__ cb, int mq, int mk, int mv,
                          float* __restrict__ qmap, float* __restrict__ kmap,
                          float* __restrict__ vmap) {
    __shared__ float sM[3][1024];
    __shared__ float sc[3][32];
    for (int p = threadIdx.x; p < 1024; p += blockDim.x) {
        sM[0][p] = cb[CB_MATS + mq * 1024 + p];
        sM[1][p] = cb[CB_MATS + mk * 1024 + p];
        sM[2][p] = cb[CB_MATS + mv * 1024 + p];
    }
    if (threadIdx.x < 32) {
        sc[0][threadIdx.x] = cb[CB_CVEC + mq * 32 + threadIdx.x];
        sc[1][threadIdx.x] = cb[CB_CVEC + mk * 32 + threadIdx.x];
        sc[2][threadIdx.x] = cb[CB_CVEC + mv * 32 + threadIdx.x];
    }
    __syncthreads();
    int b = blockIdx.y;
    int i = blockIdx.x * blockDim.x + threadIdx.x;
    if (i >= n) return;

    float x[C];
    const float* f = feats + ((size_t)b * n + i) * C;
    float mu = 0.f;
    #pragma unroll
    for (int c = 0; c < C; ++c) { x[c] = f[c]; mu += x[c]; }
    mu *= (1.0f / C);
    float var = 0.f;
    #pragma unroll
    for (int c = 0; c < C; ++c) { float d = x[c] - mu; var += d * d; }
    var *= (1.0f / C);
    float inv = 1.0f / sqrtf(var + EPS);
    #pragma unroll
    for (int c = 0; c < C; ++c) x[c] = (x[c] - mu) * inv * lnw[c] + lnb[c];

    float* outs[3] = { qmap, kmap, vmap };
    #pragma unroll
    for (int m = 0; m < 3; ++m) {
        float* o = outs[m] + ((size_t)b * n + i) * C;
        #pragma unroll
        for (int r = 0; r < C; ++r) {
            float s = sc[m][r];
            #pragma unroll
            for (int d = 0; d < C; ++d) s += sM[m][r * C + d] * x[d];
            o[r] = s;
        }
    }
}

// ---------- dynamic-lidar mask: 5x5 window (mod dims+1 wraparound!) ----------
// ra_dy is a jnp bool staged as int32 by the harness ("integer -> const int*").
__global__ void dy_mask_k(const int* __restrict__ ra_coors, const int* __restrict__ ra_dy,
                          const int* __restrict__ li_grid, uint8_t* __restrict__ mask) {
    int b = blockIdx.y;
    int r = blockIdx.x * blockDim.x + threadIdx.x;
    if (r >= NR) return;
    if (ra_dy[(size_t)b * NR + r] == 0) return;
    int x = ra_coors[((size_t)b * NR + r) * 2 + 0];
    int y = ra_coors[((size_t)b * NR + r) * 2 + 1];
    #pragma unroll
    for (int dx = -2; dx <= 2; ++dx) {
        #pragma unroll
        for (int dy = -2; dy <= 2; ++dy) {
            int sx = x + dx; sx = (sx < 0) ? sx + (Hh + 1) : (sx >= Hh + 1 ? sx - (Hh + 1) : sx);
            int sy = y + dy; sy = (sy < 0) ? sy + (Ww + 1) : (sy >= Ww + 1 ? sy - (Ww + 1) : sy);
            if (sx < Hh && sy < Ww) {
                int idx = li_grid[(size_t)b * Hh * Ww + sx * Ww + sy];
                if (idx >= 0) mask[(size_t)b * NL + idx] = 1;
            }
        }
    }
}

// ---------- fused gather + MHA + out-proj + scatter ----------
__global__ void attn_k(const float* __restrict__ qmap, const float* __restrict__ kmap,
                       const float* __restrict__ vmap, const int* __restrict__ q_coors,
                       const int* __restrict__ kv_grid, const float* __restrict__ cb,
                       int pe_off, int kinv_off, int vinv_off,
                       const float* __restrict__ Wo, const float* __restrict__ bo,
                       const uint8_t* __restrict__ mask, float* __restrict__ canvas,
                       int nq, int nkv) {
    __shared__ float sWo[1024];
    __shared__ float sbo[32], skinv[32], svinv[32];
    __shared__ float spe[9 * 32];
    for (int p = threadIdx.x; p < 1024; p += blockDim.x) sWo[p] = Wo[p];
    if (threadIdx.x < 32) {
        sbo[threadIdx.x]   = bo[threadIdx.x];
        skinv[threadIdx.x] = cb[kinv_off + threadIdx.x];
        svinv[threadIdx.x] = cb[vinv_off + threadIdx.x];
    }
    for (int p = threadIdx.x; p < 288; p += blockDim.x) spe[p] = cb[pe_off + p];
    __syncthreads();

    int b = blockIdx.y;
    int i = blockIdx.x * blockDim.x + threadIdx.x;
    if (i >= nq) return;
    if (mask && !mask[(size_t)b * NL + i]) return;   // branch-1: non-dy outputs stay zero

    int x = q_coors[((size_t)b * nq + i) * 2 + 0];
    int y = q_coors[((size_t)b * nq + i) * 2 + 1];

    int nidx[9];
    #pragma unroll
    for (int j = 0; j < 9; ++j) {
        int sx = x + DX9[j], sy = y + DY9[j];
        nidx[j] = (sx >= 0 && sx < Hh && sy >= 0 && sy < Ww)
                  ? kv_grid[(size_t)b * Hh * Ww + sx * Ww + sy] : -1;
    }

    float qp[C];
    const float* qpp = qmap + ((size_t)b * nq + i) * C;
    #pragma unroll
    for (int c = 0; c < C; ++c) qp[c] = qpp[c];

    // pass 1: scores (invalid slots use bias-only K — reference does NOT mask attention)
    float sc0[9], sc1[9];
    #pragma unroll
    for (int j = 0; j < 9; ++j) {
        int idx = nidx[j];
        const float* kp = (idx >= 0) ? (kmap + ((size_t)b * nkv + idx) * C) : skinv;
        float s0 = 0.f, s1 = 0.f;
        #pragma unroll
        for (int d = 0; d < 16; ++d) { s0 += qp[d] * kp[d]; s1 += qp[16 + d] * kp[16 + d]; }
        sc0[j] = s0 * SCALE; sc1[j] = s1 * SCALE;
    }
    // softmax per head over 9
    float m0 = sc0[0], m1 = sc1[0];
    #pragma unroll
    for (int j = 1; j < 9; ++j) { m0 = fmaxf(m0, sc0[j]); m1 = fmaxf(m1, sc1[j]); }
    float sum0 = 0.f, sum1 = 0.f;
    #pragma unroll
    for (int j = 0; j < 9; ++j) {
        sc0[j] = expf(sc0[j] - m0); sum0 += sc0[j];
        sc1[j] = expf(sc1[j] - m1); sum1 += sc1[j];
    }
    float r0 = 1.0f / sum0, r1 = 1.0f / sum1;

    // pass 2: weighted V (pos-enc added to valid slots only, pre-projected)
    float o[C];
    #pragma unroll
    for (int c = 0; c < C; ++c) o[c] = 0.f;
    #pragma unroll
    for (int j = 0; j < 9; ++j) {
        float a0 = sc0[j] * r0, a1 = sc1[j] * r1;
        int idx = nidx[j];
        if (idx >= 0) {
            const float* vp = vmap + ((size_t)b * nkv + idx) * C;
            #pragma unroll
            for (int d = 0; d < 16; ++d) {
                o[d]      += a0 * (vp[d]      + spe[j * 32 + d]);
                o[16 + d] += a1 * (vp[16 + d] + spe[j * 32 + 16 + d]);
            }
        } else {
            #pragma unroll
            for (int d = 0; d < 16; ++d) {
                o[d]      += a0 * svinv[d];
                o[16 + d] += a1 * svinv[16 + d];
            }
        }
    }

    // out-proj + scatter to (B,C,H,W) canvas
    size_t base = (size_t)b * C * Hh * Ww + (size_t)x * Ww + y;
    #pragma unroll
    for (int r = 0; r < C; ++r) {
        float s = sbo[r];
        #pragma unroll
        for (int c = 0; c < C; ++c) s += sWo[r * C + c] * o[c];
        canvas[base + (size_t)r * Hh * Ww] = s;
    }
}

extern "C" void kernel_launch(void* const* d_in, const int* in_sizes, int n_in,
                              void* d_out, int out_size, void* d_ws, size_t ws_size,
                              hipStream_t stream) {
    const float*   li_f  = (const float*)d_in[0];
    const int*     li_c  = (const int*)d_in[1];
    const float*   ra_f  = (const float*)d_in[2];
    const int*     ra_c  = (const int*)d_in[3];
    const int*     ra_dy = (const int*)d_in[4];   // jnp bool staged as int32
    const float* ln_li_w = (const float*)d_in[5];
    const float* ln_li_b = (const float*)d_in[6];
    const float* ln_ra_w = (const float*)d_in[7];
    const float* ln_ra_b = (const float*)d_in[8];
    const float* q1w = (const float*)d_in[9],  *q1b = (const float*)d_in[10];
    const float* k1w = (const float*)d_in[11], *k1b = (const float*)d_in[12];
    const float* v1w = (const float*)d_in[13], *v1b = (const float*)d_in[14];
    const float* q2w = (const float*)d_in[15], *q2b = (const float*)d_in[16];
    const float* k2w = (const float*)d_in[17], *k2b = (const float*)d_in[18];
    const float* v2w = (const float*)d_in[19], *v2b = (const float*)d_in[20];
    const float* posw = (const float*)d_in[21], *posb = (const float*)d_in[22];
    const float* a1iw = (const float*)d_in[23], *a1ib = (const float*)d_in[24];
    const float* a1ow = (const float*)d_in[25], *a1ob = (const float*)d_in[26];
    const float* a2iw = (const float*)d_in[27], *a2ib = (const float*)d_in[28];
    const float* a2ow = (const float*)d_in[29], *a2ob = (const float*)d_in[30];

    // ---- workspace carve-up (256B aligned) ----
    char* ws = (char*)d_ws;
    size_t off = 0;
    auto carve = [&](size_t bytes) { void* p = ws + off; off += (bytes + 255) & ~(size_t)255; return p; };
    int*     li_grid = (int*)carve((size_t)B * Hh * Ww * 4);   // contiguous with ra_grid
    int*     ra_grid = (int*)carve((size_t)B * Hh * Ww * 4);
    uint8_t* mask    = (uint8_t*)carve((size_t)B * NL);
    float*   cb      = (float*)carve((size_t)CB_TOT * 4);
    float*   qp1 = (float*)carve((size_t)B * NL * C * 4);
    float*   kp1 = (float*)carve((size_t)B * NR * C * 4);
    float*   vp1 = (float*)carve((size_t)B * NR * C * 4);
    float*   qp2 = (float*)carve((size_t)B * NR * C * 4);
    float*   kp2 = (float*)carve((size_t)B * NL * C * 4);
    float*   vp2 = (float*)carve((size_t)B * NL * C * 4);
    (void)ws_size; (void)n_in; (void)in_sizes;

    float* out_li = (float*)d_out;
    float* out_ra = out_li + (size_t)B * C * Hh * Ww;

    // zero output canvases; grids to -1; mask to 0
    hipMemsetAsync(d_out, 0, (size_t)out_size * sizeof(float), stream);
    hipMemsetAsync(li_grid, 0xFF, (size_t)2 * B * Hh * Ww * 4, stream);  // li+ra contiguous
    hipMemsetAsync(mask, 0, (size_t)B * NL, stream);

    // constants
    combine_mats_k<<<dim3(6), dim3(1024), 0, stream>>>(a1iw, a2iw, q1w, k1w, v1w, q2w, k2w, v2w, cb);
    combine_vecs_k<<<dim3(1), dim3(1024), 0, stream>>>(a1iw, a1ib, a2iw, a2ib,
                                                       q1b, k1b, v1b, q2b, k2b, v2b, posw, posb, cb);
    // grids
    build_grid_k<<<dim3((NL + 255) / 256, B), dim3(256), 0, stream>>>(li_c, NL, li_grid);
    build_grid_k<<<dim3((NR + 255) / 256, B), dim3(256), 0, stream>>>(ra_c, NR, ra_grid);

    // per-pillar LN + fused projections
    // lidar feeds: q of branch1 (M0), k/v of branch2 (M4, M5)
    ln_proj_k<<<dim3((NL + 255) / 256, B), dim3(256), 0, stream>>>(li_f, NL, ln_li_w, ln_li_b,
                                                                   cb, 0, 4, 5, qp1, kp2, vp2);
    // radar feeds: q of branch2 (M3), k/v of branch1 (M1, M2)
    ln_proj_k<<<dim3((NR + 255) / 256, B), dim3(256), 0, stream>>>(ra_f, NR, ln_ra_w, ln_ra_b,
                                                                   cb, 3, 1, 2, qp2, kp1, vp1);
    // dynamic mask (5x5, mod-513 wrap)
    dy_mask_k<<<dim3((NR + 255) / 256, B), dim3(256), 0, stream>>>(ra_c, ra_dy, li_grid, mask);

    // branch 1: lidar queries x radar 3x3 neighbors -> img_li (masked by dy)
    attn_k<<<dim3((NL + 255) / 256, B), dim3(256), 0, stream>>>(
        qp1, kp1, vp1, li_c, ra_grid, cb, CB_PE1, CB_INV + 0, CB_INV + 32,
        a1ow, a1ob, mask, out_li, NL, NR);
    // branch 2: radar queries x lidar 3x3 neighbors -> img_ra (no mask)
    attn_k<<<dim3((NR + 255) / 256, B), dim3(256), 0, stream>>>(
        qp2, kp2, vp2, ra_c, li_grid, cb, CB_PE2, CB_INV + 64, CB_INV + 96,
        a2ow, a2ob, nullptr, out_ra, NR, NL);
}

// Round 4
// 375.150 us; speedup vs baseline: 1.0239x; 1.0239x over previous
//
#include <hip/hip_runtime.h>
#include <stdint.h>

// ---- problem constants ----
constexpr int Hh = 512, Ww = 512;     // pseudo image dims
constexpr int C  = 32;                // channels
constexpr int B  = 2;
constexpr int NL = 50000;
constexpr int NR = 20000;
constexpr float EPS = 1e-5f;
constexpr float SCALE = 0.25f;        // 1/sqrt(16)

// combined-constant block layout (float offsets) in ws
constexpr int CB_MATS = 0;        // 6 x 1024  (Mq1,Mk1,Mv1,Mq2,Mk2,Mv2)
constexpr int CB_CVEC = 6144;     // 6 x 32    (cq1,ck1,cv1,cq2,ck2,cv2)
constexpr int CB_PE1  = 6336;     // 9 x 32    projected pos-enc, branch 1
constexpr int CB_PE2  = 6624;     // 9 x 32    branch 2
constexpr int CB_INV  = 6912;     // kinv1,vinv1,kinv2,vinv2 (4 x 32)
constexpr int CB_TOT  = 7040;

// 3x3 INDEX_SHIFT order from reference
__device__ __constant__ int DX9[9] = {0,-1,1,0,-1,1,0,-1,1};
__device__ __constant__ int DY9[9] = {0,0,0,1,1,1,-1,-1,-1};

// ---------- build both coord->pillar grids (pre-memset to -1) ----------
__global__ void build_grids_k(const int* __restrict__ li_c, const int* __restrict__ ra_c,
                              int* __restrict__ li_grid, int* __restrict__ ra_grid) {
    int b = blockIdx.y;
    int i = blockIdx.x * blockDim.x + threadIdx.x;
    if (i < NL) {
        int x = li_c[((size_t)b * NL + i) * 2 + 0];
        int y = li_c[((size_t)b * NL + i) * 2 + 1];
        li_grid[(size_t)b * Hh * Ww + x * Ww + y] = i;
    } else if (i < NL + NR) {
        int j = i - NL;
        int x = ra_c[((size_t)b * NR + j) * 2 + 0];
        int y = ra_c[((size_t)b * NR + j) * 2 + 1];
        ra_grid[(size_t)b * Hh * Ww + x * Ww + y] = j;
    }
}

// ---------- all weight-combination constants in one kernel ----------
// blocks 0..5: M_m = A_m @ W_m (32x32 each). block 6: bias vecs / pos-enc / inv biases.
__global__ void const_k(const float* __restrict__ a1w, const float* __restrict__ a1b,
                        const float* __restrict__ a2w, const float* __restrict__ a2b,
                        const float* __restrict__ q1w, const float* __restrict__ q1b,
                        const float* __restrict__ k1w, const float* __restrict__ k1b,
                        const float* __restrict__ v1w, const float* __restrict__ v1b,
                        const float* __restrict__ q2w, const float* __restrict__ q2b,
                        const float* __restrict__ k2w, const float* __restrict__ k2b,
                        const float* __restrict__ v2w, const float* __restrict__ v2b,
                        const float* __restrict__ posw, const float* __restrict__ posb,
                        float* __restrict__ cb) {
    int m = blockIdx.x;
    int t = threadIdx.x;
    if (m < 6) {
        const float* A = (m < 3 ? a1w : a2w) + (m % 3) * C * C;
        const float* Wm;
        switch (m) { case 0: Wm=q1w; break; case 1: Wm=k1w; break; case 2: Wm=v1w; break;
                     case 3: Wm=q2w; break; case 4: Wm=k2w; break; default: Wm=v2w; }
        int r = t >> 5, d = t & 31;
        float s = 0.f;
        #pragma unroll
        for (int c = 0; c < C; ++c) s += A[r * C + c] * Wm[c * C + d];
        cb[CB_MATS + m * 1024 + r * C + d] = s;
        return;
    }
    if (t < 192) {                                   // c_m = A_m @ b_m + a_b section
        int mm = t / 32, r = t & 31;
        const float* A  = (mm < 3 ? a1w : a2w) + (mm % 3) * C * C;
        const float* ab = (mm < 3 ? a1b : a2b) + (mm % 3) * C;
        const float* bv = (mm == 0 ? q1b : mm == 1 ? k1b : mm == 2 ? v1b
                         : mm == 3 ? q2b : mm == 4 ? k2b : v2b);
        float s = ab[r];
        #pragma unroll
        for (int c = 0; c < C; ++c) s += A[r * C + c] * bv[c];
        cb[CB_CVEC + mm * 32 + r] = s;
    } else if (t < 480) {                            // pe9v1 = A1v @ pe9[j]
        int u = t - 192; int j = u >> 5, r = u & 31;
        const float* A = a1w + 2 * C * C;
        float sx = (float)DX9[j], sy = (float)DY9[j];
        float s = 0.f;
        #pragma unroll
        for (int c = 0; c < C; ++c) {
            float pe = posw[c * 2 + 0] * sx + posw[c * 2 + 1] * sy + posb[c];
            s += A[r * C + c] * pe;
        }
        cb[CB_PE1 + j * 32 + r] = s;
    } else if (t < 768) {                            // pe9v2 = A2v @ pe9[j]
        int u = t - 480; int j = u >> 5, r = u & 31;
        const float* A = a2w + 2 * C * C;
        float sx = (float)DX9[j], sy = (float)DY9[j];
        float s = 0.f;
        #pragma unroll
        for (int c = 0; c < C; ++c) {
            float pe = posw[c * 2 + 0] * sx + posw[c * 2 + 1] * sy + posb[c];
            s += A[r * C + c] * pe;
        }
        cb[CB_PE2 + j * 32 + r] = s;
    } else if (t < 896) {                            // invalid-slot biases (in_proj k/v bias)
        int u = t - 768; int mm = u >> 5, r = u & 31;
        cb[CB_INV + u] = (mm == 0 ? a1b[32 + r] : mm == 1 ? a1b[64 + r]
                        : mm == 2 ? a2b[32 + r] : a2b[64 + r]);
    }
}

// ---------- LayerNorm + 3 fused 32x32 matvecs per pillar ----------
__global__ void ln_proj_k(const float* __restrict__ feats, int n,
                          const float* __restrict__ lnw, const float* __restrict__ lnb,
                          const float* __restrict__ cb, int mq, int mk, int mv,
                          float* __restrict__ qmap, float* __restrict__ kmap,
                          float* __restrict__ vmap) {
    __shared__ float sM[3][1024];
    __shared__ float sc[3][32];
    for (int p = threadIdx.x; p < 1024; p += blockDim.x) {
        sM[0][p] = cb[CB_MATS + mq * 1024 + p];
        sM[1][p] = cb[CB_MATS + mk * 1024 + p];
        sM[2][p] = cb[CB_MATS + mv * 1024 + p];
    }
    if (threadIdx.x < 32) {
        sc[0][threadIdx.x] = cb[CB_CVEC + mq * 32 + threadIdx.x];
        sc[1][threadIdx.x] = cb[CB_CVEC + mk * 32 + threadIdx.x];
        sc[2][threadIdx.x] = cb[CB_CVEC + mv * 32 + threadIdx.x];
    }
    __syncthreads();
    int b = blockIdx.y;
    int i = blockIdx.x * blockDim.x + threadIdx.x;
    if (i >= n) return;

    float x[C];
    const float4* f4 = (const float4*)(feats + ((size_t)b * n + i) * C);
    #pragma unroll
    for (int q = 0; q < 8; ++q) {
        float4 t = f4[q];
        x[4*q] = t.x; x[4*q+1] = t.y; x[4*q+2] = t.z; x[4*q+3] = t.w;
    }
    float mu = 0.f;
    #pragma unroll
    for (int c = 0; c < C; ++c) mu += x[c];
    mu *= (1.0f / C);
    float var = 0.f;
    #pragma unroll
    for (int c = 0; c < C; ++c) { float d = x[c] - mu; var += d * d; }
    var *= (1.0f / C);
    float inv = 1.0f / sqrtf(var + EPS);
    #pragma unroll
    for (int c = 0; c < C; ++c) x[c] = (x[c] - mu) * inv * lnw[c] + lnb[c];

    float* outs[3] = { qmap, kmap, vmap };
    #pragma unroll
    for (int m = 0; m < 3; ++m) {
        float4* o4 = (float4*)(outs[m] + ((size_t)b * n + i) * C);
        #pragma unroll
        for (int rq = 0; rq < 8; ++rq) {
            float4 t;
            float* tp = &t.x;
            #pragma unroll
            for (int rr = 0; rr < 4; ++rr) {
                int r = rq * 4 + rr;
                float s = sc[m][r];
                #pragma unroll
                for (int d = 0; d < C; ++d) s += sM[m][r * C + d] * x[d];
                tp[rr] = s;
            }
            o4[rq] = t;
        }
    }
}

// ---------- dynamic-lidar mask: 5x5 window (mod dims+1 wraparound!) ----------
// ra_dy is a jnp bool staged as int32 by the harness ("integer -> const int*").
__global__ void dy_mask_k(const int* __restrict__ ra_coors, const int* __restrict__ ra_dy,
                          const int* __restrict__ li_grid, uint8_t* __restrict__ mask) {
    int b = blockIdx.y;
    int r = blockIdx.x * blockDim.x + threadIdx.x;
    if (r >= NR) return;
    if (ra_dy[(size_t)b * NR + r] == 0) return;
    int x = ra_coors[((size_t)b * NR + r) * 2 + 0];
    int y = ra_coors[((size_t)b * NR + r) * 2 + 1];
    #pragma unroll
    for (int dx = -2; dx <= 2; ++dx) {
        #pragma unroll
        for (int dy = -2; dy <= 2; ++dy) {
            int sx = x + dx; sx = (sx < 0) ? sx + (Hh + 1) : (sx >= Hh + 1 ? sx - (Hh + 1) : sx);
            int sy = y + dy; sy = (sy < 0) ? sy + (Ww + 1) : (sy >= Ww + 1 ? sy - (Ww + 1) : sy);
            if (sx < Hh && sy < Ww) {
                int idx = li_grid[(size_t)b * Hh * Ww + sx * Ww + sy];
                if (idx >= 0) mask[(size_t)b * NL + idx] = 1;
            }
        }
    }
}

// ---------- fused gather + MHA + out-proj -> per-pillar feature [N,C] ----------
__global__ void attn_k(const float* __restrict__ qmap, const float* __restrict__ kmap,
                       const float* __restrict__ vmap, const int* __restrict__ q_coors,
                       const int* __restrict__ kv_grid, const float* __restrict__ cb,
                       int pe_off, int kinv_off, int vinv_off,
                       const float* __restrict__ Wo, const float* __restrict__ bo,
                       const uint8_t* __restrict__ mask, float* __restrict__ feat,
                       int nq, int nkv) {
    __shared__ float sWo[1024];
    __shared__ float sbo[32], skinv[32], svinv[32];
    __shared__ float spe[9 * 32];
    for (int p = threadIdx.x; p < 1024; p += blockDim.x) sWo[p] = Wo[p];
    if (threadIdx.x < 32) {
        sbo[threadIdx.x]   = bo[threadIdx.x];
        skinv[threadIdx.x] = cb[kinv_off + threadIdx.x];
        svinv[threadIdx.x] = cb[vinv_off + threadIdx.x];
    }
    for (int p = threadIdx.x; p < 288; p += blockDim.x) spe[p] = cb[pe_off + p];
    __syncthreads();

    int b = blockIdx.y;
    int i = blockIdx.x * blockDim.x + threadIdx.x;
    if (i >= nq) return;
    float4* o4 = (float4*)(feat + ((size_t)b * nq + i) * C);
    if (mask && !mask[(size_t)b * NL + i]) {         // branch-1: non-dy pillars output zero
        float4 z = {0.f, 0.f, 0.f, 0.f};
        #pragma unroll
        for (int q = 0; q < 8; ++q) o4[q] = z;
        return;
    }

    int x = q_coors[((size_t)b * nq + i) * 2 + 0];
    int y = q_coors[((size_t)b * nq + i) * 2 + 1];

    int nidx[9];
    #pragma unroll
    for (int j = 0; j < 9; ++j) {
        int sx = x + DX9[j], sy = y + DY9[j];
        nidx[j] = (sx >= 0 && sx < Hh && sy >= 0 && sy < Ww)
                  ? kv_grid[(size_t)b * Hh * Ww + sx * Ww + sy] : -1;
    }

    float qp[C];
    const float4* qp4 = (const float4*)(qmap + ((size_t)b * nq + i) * C);
    #pragma unroll
    for (int q = 0; q < 8; ++q) {
        float4 t = qp4[q];
        qp[4*q] = t.x; qp[4*q+1] = t.y; qp[4*q+2] = t.z; qp[4*q+3] = t.w;
    }

    // pass 1: scores (invalid slots use bias-only K — reference does NOT mask attention)
    float sc0[9], sc1[9];
    #pragma unroll
    for (int j = 0; j < 9; ++j) {
        int idx = nidx[j];
        const float* kp = (idx >= 0) ? (kmap + ((size_t)b * nkv + idx) * C) : skinv;
        float s0 = 0.f, s1 = 0.f;
        #pragma unroll
        for (int d = 0; d < 16; ++d) { s0 += qp[d] * kp[d]; s1 += qp[16 + d] * kp[16 + d]; }
        sc0[j] = s0 * SCALE; sc1[j] = s1 * SCALE;
    }
    // softmax per head over 9
    float m0 = sc0[0], m1 = sc1[0];
    #pragma unroll
    for (int j = 1; j < 9; ++j) { m0 = fmaxf(m0, sc0[j]); m1 = fmaxf(m1, sc1[j]); }
    float sum0 = 0.f, sum1 = 0.f;
    #pragma unroll
    for (int j = 0; j < 9; ++j) {
        sc0[j] = expf(sc0[j] - m0); sum0 += sc0[j];
        sc1[j] = expf(sc1[j] - m1); sum1 += sc1[j];
    }
    float r0 = 1.0f / sum0, r1 = 1.0f / sum1;

    // pass 2: weighted V (pos-enc added to valid slots only, pre-projected)
    float o[C];
    #pragma unroll
    for (int c = 0; c < C; ++c) o[c] = 0.f;
    #pragma unroll
    for (int j = 0; j < 9; ++j) {
        float a0 = sc0[j] * r0, a1 = sc1[j] * r1;
        int idx = nidx[j];
        if (idx >= 0) {
            const float* vp = vmap + ((size_t)b * nkv + idx) * C;
            #pragma unroll
            for (int d = 0; d < 16; ++d) {
                o[d]      += a0 * (vp[d]      + spe[j * 32 + d]);
                o[16 + d] += a1 * (vp[16 + d] + spe[j * 32 + 16 + d]);
            }
        } else {
            #pragma unroll
            for (int d = 0; d < 16; ++d) {
                o[d]      += a0 * svinv[d];
                o[16 + d] += a1 * svinv[16 + d];
            }
        }
    }

    // out-proj, coalesced [N,C] store
    #pragma unroll
    for (int rq = 0; rq < 8; ++rq) {
        float4 t;
        float* tp = &t.x;
        #pragma unroll
        for (int rr = 0; rr < 4; ++rr) {
            int r = rq * 4 + rr;
            float s = sbo[r];
            #pragma unroll
            for (int c = 0; c < C; ++c) s += sWo[r * C + c] * o[c];
            tp[rr] = s;
        }
        o4[rq] = t;
    }
}

// ---------- densify: thread per cell, coalesced canvas writes (zeros included) ----------
__global__ void canvas_k(const int* __restrict__ li_grid, const int* __restrict__ ra_grid,
                         const float* __restrict__ feat1, const float* __restrict__ feat2,
                         float* __restrict__ out_li, float* __restrict__ out_ra) {
    int b = blockIdx.y;
    int cell = blockIdx.x * blockDim.x + threadIdx.x;
    if (cell >= Hh * Ww) return;
    size_t gidx = (size_t)b * Hh * Ww + cell;
    size_t obase = (size_t)b * C * Hh * Ww + cell;

    int li = li_grid[gidx];
    float v[C];
    if (li >= 0) {
        const float4* f = (const float4*)(feat1 + ((size_t)b * NL + li) * C);
        #pragma unroll
        for (int q = 0; q < 8; ++q) {
            float4 t = f[q];
            v[4*q] = t.x; v[4*q+1] = t.y; v[4*q+2] = t.z; v[4*q+3] = t.w;
        }
    } else {
        #pragma unroll
        for (int c = 0; c < C; ++c) v[c] = 0.f;
    }
    #pragma unroll
    for (int c = 0; c < C; ++c) out_li[obase + (size_t)c * Hh * Ww] = v[c];

    int ra = ra_grid[gidx];
    if (ra >= 0) {
        const float4* f = (const float4*)(feat2 + ((size_t)b * NR + ra) * C);
        #pragma unroll
        for (int q = 0; q < 8; ++q) {
            float4 t = f[q];
            v[4*q] = t.x; v[4*q+1] = t.y; v[4*q+2] = t.z; v[4*q+3] = t.w;
        }
    } else {
        #pragma unroll
        for (int c = 0; c < C; ++c) v[c] = 0.f;
    }
    #pragma unroll
    for (int c = 0; c < C; ++c) out_ra[obase + (size_t)c * Hh * Ww] = v[c];
}

extern "C" void kernel_launch(void* const* d_in, const int* in_sizes, int n_in,
                              void* d_out, int out_size, void* d_ws, size_t ws_size,
                              hipStream_t stream) {
    const float*   li_f  = (const float*)d_in[0];
    const int*     li_c  = (const int*)d_in[1];
    const float*   ra_f  = (const float*)d_in[2];
    const int*     ra_c  = (const int*)d_in[3];
    const int*     ra_dy = (const int*)d_in[4];   // jnp bool staged as int32
    const float* ln_li_w = (const float*)d_in[5];
    const float* ln_li_b = (const float*)d_in[6];
    const float* ln_ra_w = (const float*)d_in[7];
    const float* ln_ra_b = (const float*)d_in[8];
    const float* q1w = (const float*)d_in[9],  *q1b = (const float*)d_in[10];
    const float* k1w = (const float*)d_in[11], *k1b = (const float*)d_in[12];
    const float* v1w = (const float*)d_in[13], *v1b = (const float*)d_in[14];
    const float* q2w = (const float*)d_in[15], *q2b = (const float*)d_in[16];
    const float* k2w = (const float*)d_in[17], *k2b = (const float*)d_in[18];
    const float* v2w = (const float*)d_in[19], *v2b = (const float*)d_in[20];
    const float* posw = (const float*)d_in[21], *posb = (const float*)d_in[22];
    const float* a1iw = (const float*)d_in[23], *a1ib = (const float*)d_in[24];
    const float* a1ow = (const float*)d_in[25], *a1ob = (const float*)d_in[26];
    const float* a2iw = (const float*)d_in[27], *a2ib = (const float*)d_in[28];
    const float* a2ow = (const float*)d_in[29], *a2ob = (const float*)d_in[30];

    // ---- workspace carve-up (256B aligned) ----
    char* ws = (char*)d_ws;
    size_t off = 0;
    auto carve = [&](size_t bytes) { void* p = ws + off; off += (bytes + 255) & ~(size_t)255; return p; };
    int*     li_grid = (int*)carve((size_t)B * Hh * Ww * 4);   // contiguous with ra_grid
    int*     ra_grid = (int*)carve((size_t)B * Hh * Ww * 4);
    uint8_t* mask    = (uint8_t*)carve((size_t)B * NL);
    float*   cb      = (float*)carve((size_t)CB_TOT * 4);
    float*   qp1   = (float*)carve((size_t)B * NL * C * 4);
    float*   kp1   = (float*)carve((size_t)B * NR * C * 4);
    float*   vp1   = (float*)carve((size_t)B * NR * C * 4);
    float*   qp2   = (float*)carve((size_t)B * NR * C * 4);
    float*   kp2   = (float*)carve((size_t)B * NL * C * 4);
    float*   vp2   = (float*)carve((size_t)B * NL * C * 4);
    float*   feat1 = (float*)carve((size_t)B * NL * C * 4);
    float*   feat2 = (float*)carve((size_t)B * NR * C * 4);
    (void)ws_size; (void)n_in; (void)in_sizes; (void)out_size;

    float* out_li = (float*)d_out;
    float* out_ra = out_li + (size_t)B * C * Hh * Ww;

    // grids to -1; mask to 0 (no d_out memset — canvas_k writes every cell)
    hipMemsetAsync(li_grid, 0xFF, (size_t)2 * B * Hh * Ww * 4, stream);  // li+ra contiguous
    hipMemsetAsync(mask, 0, (size_t)B * NL, stream);

    // constants (7 blocks: 6 matrix-combines + 1 vec block)
    const_k<<<dim3(7), dim3(1024), 0, stream>>>(a1iw, a1ib, a2iw, a2ib,
                                                q1w, q1b, k1w, k1b, v1w, v1b,
                                                q2w, q2b, k2w, k2b, v2w, v2b,
                                                posw, posb, cb);
    // both grids in one launch
    build_grids_k<<<dim3((NL + NR + 255) / 256, B), dim3(256), 0, stream>>>(li_c, ra_c, li_grid, ra_grid);

    // per-pillar LN + fused projections
    ln_proj_k<<<dim3((NL + 255) / 256, B), dim3(256), 0, stream>>>(li_f, NL, ln_li_w, ln_li_b,
                                                                   cb, 0, 4, 5, qp1, kp2, vp2);
    ln_proj_k<<<dim3((NR + 255) / 256, B), dim3(256), 0, stream>>>(ra_f, NR, ln_ra_w, ln_ra_b,
                                                                   cb, 3, 1, 2, qp2, kp1, vp1);
    // dynamic mask (5x5, mod-513 wrap)
    dy_mask_k<<<dim3((NR + 255) / 256, B), dim3(256), 0, stream>>>(ra_c, ra_dy, li_grid, mask);

    // branch 1: lidar queries x radar 3x3 neighbors -> feat1 (zeros for non-dy)
    attn_k<<<dim3((NL + 255) / 256, B), dim3(256), 0, stream>>>(
        qp1, kp1, vp1, li_c, ra_grid, cb, CB_PE1, CB_INV + 0, CB_INV + 32,
        a1ow, a1ob, mask, feat1, NL, NR);
    // branch 2: radar queries x lidar 3x3 neighbors -> feat2
    attn_k<<<dim3((NR + 255) / 256, B), dim3(256), 0, stream>>>(
        qp2, kp2, vp2, ra_c, li_grid, cb, CB_PE2, CB_INV + 64, CB_INV + 96,
        a2ow, a2ob, nullptr, feat2, NR, NL);

    // densify both canvases with coalesced writes
    canvas_k<<<dim3((Hh * Ww + 255) / 256, B), dim3(256), 0, stream>>>(
        li_grid, ra_grid, feat1, feat2, out_li, out_ra);
}

// Round 5
// 331.948 us; speedup vs baseline: 1.1571x; 1.1301x over previous
//
#include <hip/hip_runtime.h>
#include <stdint.h>

// ---- problem constants ----
constexpr int Hh = 512, Ww = 512;     // pseudo image dims
constexpr int HW = Hh * Ww;
constexpr int C  = 32;                // channels
constexpr int B  = 2;
constexpr int NL = 50000;
constexpr int NR = 20000;
constexpr float EPS = 1e-5f;
constexpr float SCALE = 0.25f;        // 1/sqrt(16)

// block-range sizes
constexpr int GBL = (NL + NR + 255) / 256;   // grid-build blocks per batch
constexpr int LB  = (NL + 255) / 256;        // lidar blocks
constexpr int RB  = (NR + 255) / 256;        // radar blocks

// combined-constant block layout (float offsets) in ws
constexpr int CB_MATS = 0;        // 6 x 1024  (Mq1,Mk1,Mv1,Mq2,Mk2,Mv2)
constexpr int CB_CVEC = 6144;     // 6 x 32    (cq1,ck1,cv1,cq2,ck2,cv2)
constexpr int CB_PE1  = 6336;     // 9 x 32    projected pos-enc, branch 1
constexpr int CB_PE2  = 6624;     // 9 x 32    branch 2
constexpr int CB_INV  = 6912;     // kinv1,vinv1,kinv2,vinv2 (4 x 32)
constexpr int CB_TOT  = 7040;

// 3x3 INDEX_SHIFT order from reference
__device__ __constant__ int DX9[9] = {0,-1,1,0,-1,1,0,-1,1};
__device__ __constant__ int DY9[9] = {0,0,0,1,1,1,-1,-1,-1};

// ---------- kernel A: grids + radar-dy grid + all weight-combination constants ----------
// blockIdx.x < GBL           : scatter pillar indices into grids (per batch y)
// blockIdx.x in [GBL,GBL+6)  : M_m = A_m @ W_m   (y==0 only)
// blockIdx.x == GBL+6        : bias vecs / pos-enc / inv biases (y==0 only)
__global__ void setup_k(const int* __restrict__ li_c, const int* __restrict__ ra_c,
                        const int* __restrict__ ra_dy,
                        int* __restrict__ li_grid, int* __restrict__ ra_grid,
                        uint8_t* __restrict__ rdy_grid,            // 0xFF = not dy, 0 = dy
                        const float* __restrict__ a1w, const float* __restrict__ a1b,
                        const float* __restrict__ a2w, const float* __restrict__ a2b,
                        const float* __restrict__ q1w, const float* __restrict__ q1b,
                        const float* __restrict__ k1w, const float* __restrict__ k1b,
                        const float* __restrict__ v1w, const float* __restrict__ v1b,
                        const float* __restrict__ q2w, const float* __restrict__ q2b,
                        const float* __restrict__ k2w, const float* __restrict__ k2b,
                        const float* __restrict__ v2w, const float* __restrict__ v2b,
                        const float* __restrict__ posw, const float* __restrict__ posb,
                        float* __restrict__ cb) {
    int bx = blockIdx.x, b = blockIdx.y, t = threadIdx.x;
    if (bx < GBL) {
        int i = bx * 256 + t;
        if (i < NL) {
            int x = li_c[((size_t)b * NL + i) * 2 + 0];
            int y = li_c[((size_t)b * NL + i) * 2 + 1];
            li_grid[(size_t)b * HW + x * Ww + y] = i;
        } else if (i < NL + NR) {
            int j = i - NL;
            int x = ra_c[((size_t)b * NR + j) * 2 + 0];
            int y = ra_c[((size_t)b * NR + j) * 2 + 1];
            ra_grid[(size_t)b * HW + x * Ww + y] = j;
            if (ra_dy[(size_t)b * NR + j] != 0)
                rdy_grid[(size_t)b * HW + x * Ww + y] = 0;
        }
        return;
    }
    if (b != 0) return;
    if (bx < GBL + 6) {                               // matrix combines, 4 elems/thread
        int m = bx - GBL;
        const float* A = (m < 3 ? a1w : a2w) + (m % 3) * C * C;
        const float* Wm;
        switch (m) { case 0: Wm=q1w; break; case 1: Wm=k1w; break; case 2: Wm=v1w; break;
                     case 3: Wm=q2w; break; case 4: Wm=k2w; break; default: Wm=v2w; }
        for (int p = t; p < 1024; p += 256) {
            int r = p >> 5, d = p & 31;
            float s = 0.f;
            #pragma unroll
            for (int c = 0; c < C; ++c) s += A[r * C + c] * Wm[c * C + d];
            cb[CB_MATS + m * 1024 + r * C + d] = s;
        }
        return;
    }
    // vec section: 896 slots
    for (int u = t; u < 896; u += 256) {
        if (u < 192) {                                // c_m = A_m @ b_m + a_b section
            int mm = u / 32, r = u & 31;
            const float* A  = (mm < 3 ? a1w : a2w) + (mm % 3) * C * C;
            const float* ab = (mm < 3 ? a1b : a2b) + (mm % 3) * C;
            const float* bv = (mm == 0 ? q1b : mm == 1 ? k1b : mm == 2 ? v1b
                             : mm == 3 ? q2b : mm == 4 ? k2b : v2b);
            float s = ab[r];
            #pragma unroll
            for (int c = 0; c < C; ++c) s += A[r * C + c] * bv[c];
            cb[CB_CVEC + mm * 32 + r] = s;
        } else if (u < 768) {                         // pe9v = A{1,2}v @ pe9[j]
            int w = u - 192;                          // 0..575 ; 0..287 -> br1, 288.. -> br2
            int br = w / 288; int v = w % 288; int j = v >> 5, r = v & 31;
            const float* A = (br == 0 ? a1w : a2w) + 2 * C * C;
            float sx = (float)DX9[j], sy = (float)DY9[j];
            float s = 0.f;
            #pragma unroll
            for (int c = 0; c < C; ++c) {
                float pe = posw[c * 2 + 0] * sx + posw[c * 2 + 1] * sy + posb[c];
                s += A[r * C + c] * pe;
            }
            cb[(br == 0 ? CB_PE1 : CB_PE2) + j * 32 + r] = s;
        } else {                                      // invalid-slot biases
            int v = u - 768; int mm = v >> 5, r = v & 31;
            cb[CB_INV + v] = (mm == 0 ? a1b[32 + r] : mm == 1 ? a1b[64 + r]
                            : mm == 2 ? a2b[32 + r] : a2b[64 + r]);
        }
    }
}

// ---------- kernel B: LayerNorm + 3 fused 32x32 matvecs, both modalities ----------
__global__ void ln_proj_k(const float* __restrict__ li_f, const float* __restrict__ ra_f,
                          const float* __restrict__ ln_li_w, const float* __restrict__ ln_li_b,
                          const float* __restrict__ ln_ra_w, const float* __restrict__ ln_ra_b,
                          const float* __restrict__ cb,
                          float* __restrict__ qp1, float* __restrict__ kp2, float* __restrict__ vp2,
                          float* __restrict__ qp2, float* __restrict__ kp1, float* __restrict__ vp1) {
    bool lidar = (blockIdx.x < LB);
    int n  = lidar ? NL : NR;
    int i  = (lidar ? blockIdx.x : blockIdx.x - LB) * 256 + threadIdx.x;
    int b  = blockIdx.y;
    int mq = lidar ? 0 : 3, mk = lidar ? 4 : 1, mv = lidar ? 5 : 2;
    const float* feats = lidar ? li_f : ra_f;
    const float* lnw = lidar ? ln_li_w : ln_ra_w;
    const float* lnb = lidar ? ln_li_b : ln_ra_b;
    float* o0 = lidar ? qp1 : qp2;
    float* o1 = lidar ? kp2 : kp1;
    float* o2 = lidar ? vp2 : vp1;

    __shared__ float sM[3][1024];
    __shared__ float sc[3][32];
    for (int p = threadIdx.x; p < 1024; p += blockDim.x) {
        sM[0][p] = cb[CB_MATS + mq * 1024 + p];
        sM[1][p] = cb[CB_MATS + mk * 1024 + p];
        sM[2][p] = cb[CB_MATS + mv * 1024 + p];
    }
    if (threadIdx.x < 32) {
        sc[0][threadIdx.x] = cb[CB_CVEC + mq * 32 + threadIdx.x];
        sc[1][threadIdx.x] = cb[CB_CVEC + mk * 32 + threadIdx.x];
        sc[2][threadIdx.x] = cb[CB_CVEC + mv * 32 + threadIdx.x];
    }
    __syncthreads();
    if (i >= n) return;

    float x[C];
    const float4* f4 = (const float4*)(feats + ((size_t)b * n + i) * C);
    #pragma unroll
    for (int q = 0; q < 8; ++q) {
        float4 t = f4[q];
        x[4*q] = t.x; x[4*q+1] = t.y; x[4*q+2] = t.z; x[4*q+3] = t.w;
    }
    float mu = 0.f;
    #pragma unroll
    for (int c = 0; c < C; ++c) mu += x[c];
    mu *= (1.0f / C);
    float var = 0.f;
    #pragma unroll
    for (int c = 0; c < C; ++c) { float d = x[c] - mu; var += d * d; }
    var *= (1.0f / C);
    float inv = 1.0f / sqrtf(var + EPS);
    #pragma unroll
    for (int c = 0; c < C; ++c) x[c] = (x[c] - mu) * inv * lnw[c] + lnb[c];

    float* outs[3] = { o0, o1, o2 };
    #pragma unroll
    for (int m = 0; m < 3; ++m) {
        float4* o4 = (float4*)(outs[m] + ((size_t)b * n + i) * C);
        #pragma unroll
        for (int rq = 0; rq < 8; ++rq) {
            float4 t;
            float* tp = &t.x;
            #pragma unroll
            for (int rr = 0; rr < 4; ++rr) {
                int r = rq * 4 + rr;
                float s = sc[m][r];
                #pragma unroll
                for (int d = 0; d < C; ++d) s += sM[m][r * C + d] * x[d];
                tp[rr] = s;
            }
            o4[rq] = t;
        }
    }
}

// ---------- kernel C: fused gather + MHA + out-proj, both branches ----------
// branch 1 (lidar queries) computes its dy flag inline from rdy_grid:
// lidar (lx,ly) is dy iff exists (dx,dy) in [-2,2]^2 with rdy_grid[(lx-dx)%513, (ly-dy)%513]==0
// (coordinate value 512 is invalid -> skip; matches reference's mod-(dims+1) semantics).
__global__ void attn_k(const float* __restrict__ qp1, const float* __restrict__ kp1,
                       const float* __restrict__ vp1, const float* __restrict__ qp2,
                       const float* __restrict__ kp2, const float* __restrict__ vp2,
                       const int* __restrict__ li_c, const int* __restrict__ ra_c,
                       const int* __restrict__ li_grid, const int* __restrict__ ra_grid,
                       const uint8_t* __restrict__ rdy_grid, const float* __restrict__ cb,
                       const float* __restrict__ a1ow, const float* __restrict__ a1ob,
                       const float* __restrict__ a2ow, const float* __restrict__ a2ob,
                       float* __restrict__ feat1, float* __restrict__ feat2) {
    bool br1 = (blockIdx.x < LB);
    int nq  = br1 ? NL : NR;
    int nkv = br1 ? NR : NL;
    int i   = (br1 ? blockIdx.x : blockIdx.x - LB) * 256 + threadIdx.x;
    int b   = blockIdx.y;
    const float* qmap = br1 ? qp1 : qp2;
    const float* kmap = br1 ? kp1 : kp2;
    const float* vmap = br1 ? vp1 : vp2;
    const int* q_coors  = br1 ? li_c : ra_c;
    const int* kv_grid  = br1 ? ra_grid : li_grid;
    const float* Wo = br1 ? a1ow : a2ow;
    const float* bo = br1 ? a1ob : a2ob;
    int pe_off   = br1 ? CB_PE1 : CB_PE2;
    int kinv_off = br1 ? CB_INV + 0  : CB_INV + 64;
    int vinv_off = br1 ? CB_INV + 32 : CB_INV + 96;
    float* feat  = br1 ? feat1 : feat2;

    __shared__ float sWo[1024];
    __shared__ float sbo[32], skinv[32], svinv[32];
    __shared__ float spe[9 * 32];
    for (int p = threadIdx.x; p < 1024; p += blockDim.x) sWo[p] = Wo[p];
    if (threadIdx.x < 32) {
        sbo[threadIdx.x]   = bo[threadIdx.x];
        skinv[threadIdx.x] = cb[kinv_off + threadIdx.x];
        svinv[threadIdx.x] = cb[vinv_off + threadIdx.x];
    }
    for (int p = threadIdx.x; p < 288; p += blockDim.x) spe[p] = cb[pe_off + p];
    __syncthreads();

    if (i >= nq) return;
    float4* o4 = (float4*)(feat + ((size_t)b * nq + i) * C);

    int x = q_coors[((size_t)b * nq + i) * 2 + 0];
    int y = q_coors[((size_t)b * nq + i) * 2 + 1];

    if (br1) {
        // inline dy test: 5x5 window with mod-513 wrap
        bool dy = false;
        #pragma unroll
        for (int dx = -2; dx <= 2 && !dy; ++dx) {
            int cx = x + dx;
            cx = (cx < 0) ? cx + 513 : (cx >= 513 ? cx - 513 : cx);
            if (cx == 512) continue;
            #pragma unroll
            for (int dyy = -2; dyy <= 2; ++dyy) {
                int cy = y + dyy;
                cy = (cy < 0) ? cy + 513 : (cy >= 513 ? cy - 513 : cy);
                if (cy == 512) continue;
                if (rdy_grid[(size_t)b * HW + cx * Ww + cy] == 0) { dy = true; break; }
            }
        }
        if (!dy) {
            float4 z = {0.f, 0.f, 0.f, 0.f};
            #pragma unroll
            for (int q = 0; q < 8; ++q) o4[q] = z;
            return;
        }
    }

    int nidx[9];
    #pragma unroll
    for (int j = 0; j < 9; ++j) {
        int sx = x + DX9[j], sy = y + DY9[j];
        nidx[j] = (sx >= 0 && sx < Hh && sy >= 0 && sy < Ww)
                  ? kv_grid[(size_t)b * HW + sx * Ww + sy] : -1;
    }

    float qp[C];
    const float4* qp4 = (const float4*)(qmap + ((size_t)b * nq + i) * C);
    #pragma unroll
    for (int q = 0; q < 8; ++q) {
        float4 t = qp4[q];
        qp[4*q] = t.x; qp[4*q+1] = t.y; qp[4*q+2] = t.z; qp[4*q+3] = t.w;
    }

    // pass 1: scores (invalid slots use bias-only K — reference does NOT mask attention)
    float sc0[9], sc1[9];
    #pragma unroll
    for (int j = 0; j < 9; ++j) {
        int idx = nidx[j];
        const float4* kp4 = (idx >= 0) ? (const float4*)(kmap + ((size_t)b * nkv + idx) * C)
                                       : (const float4*)skinv;
        float s0 = 0.f, s1 = 0.f;
        #pragma unroll
        for (int q = 0; q < 4; ++q) {
            float4 t = kp4[q];
            s0 += qp[4*q] * t.x + qp[4*q+1] * t.y + qp[4*q+2] * t.z + qp[4*q+3] * t.w;
        }
        #pragma unroll
        for (int q = 4; q < 8; ++q) {
            float4 t = kp4[q];
            s1 += qp[4*q] * t.x + qp[4*q+1] * t.y + qp[4*q+2] * t.z + qp[4*q+3] * t.w;
        }
        sc0[j] = s0 * SCALE; sc1[j] = s1 * SCALE;
    }
    // softmax per head over 9
    float m0 = sc0[0], m1 = sc1[0];
    #pragma unroll
    for (int j = 1; j < 9; ++j) { m0 = fmaxf(m0, sc0[j]); m1 = fmaxf(m1, sc1[j]); }
    float sum0 = 0.f, sum1 = 0.f;
    #pragma unroll
    for (int j = 0; j < 9; ++j) {
        sc0[j] = expf(sc0[j] - m0); sum0 += sc0[j];
        sc1[j] = expf(sc1[j] - m1); sum1 += sc1[j];
    }
    float r0 = 1.0f / sum0, r1 = 1.0f / sum1;

    // pass 2: weighted V (pos-enc added to valid slots only, pre-projected)
    float o[C];
    #pragma unroll
    for (int c = 0; c < C; ++c) o[c] = 0.f;
    #pragma unroll
    for (int j = 0; j < 9; ++j) {
        float a0 = sc0[j] * r0, a1 = sc1[j] * r1;
        int idx = nidx[j];
        if (idx >= 0) {
            const float4* vp4 = (const float4*)(vmap + ((size_t)b * nkv + idx) * C);
            #pragma unroll
            for (int q = 0; q < 8; ++q) {
                float4 t = vp4[q];
                float a = (q < 4) ? a0 : a1;
                o[4*q]   += a * (t.x + spe[j * 32 + 4*q]);
                o[4*q+1] += a * (t.y + spe[j * 32 + 4*q+1]);
                o[4*q+2] += a * (t.z + spe[j * 32 + 4*q+2]);
                o[4*q+3] += a * (t.w + spe[j * 32 + 4*q+3]);
            }
        } else {
            #pragma unroll
            for (int d = 0; d < 16; ++d) {
                o[d]      += a0 * svinv[d];
                o[16 + d] += a1 * svinv[16 + d];
            }
        }
    }

    // out-proj, coalesced [N,C] store
    #pragma unroll
    for (int rq = 0; rq < 8; ++rq) {
        float4 t;
        float* tp = &t.x;
        #pragma unroll
        for (int rr = 0; rr < 4; ++rr) {
            int r = rq * 4 + rr;
            float s = sbo[r];
            #pragma unroll
            for (int c = 0; c < C; ++c) s += sWo[r * C + c] * o[c];
            tp[rr] = s;
        }
        o4[rq] = t;
    }
}

// ---------- kernel D: densify, thread per cell, coalesced canvas writes ----------
__global__ void canvas_k(const int* __restrict__ li_grid, const int* __restrict__ ra_grid,
                         const float* __restrict__ feat1, const float* __restrict__ feat2,
                         float* __restrict__ out_li, float* __restrict__ out_ra) {
    int b = blockIdx.y;
    int cell = blockIdx.x * blockDim.x + threadIdx.x;
    if (cell >= HW) return;
    size_t gidx = (size_t)b * HW + cell;
    size_t obase = (size_t)b * C * HW + cell;

    int li = li_grid[gidx];
    float v[C];
    if (li >= 0) {
        const float4* f = (const float4*)(feat1 + ((size_t)b * NL + li) * C);
        #pragma unroll
        for (int q = 0; q < 8; ++q) {
            float4 t = f[q];
            v[4*q] = t.x; v[4*q+1] = t.y; v[4*q+2] = t.z; v[4*q+3] = t.w;
        }
    } else {
        #pragma unroll
        for (int c = 0; c < C; ++c) v[c] = 0.f;
    }
    #pragma unroll
    for (int c = 0; c < C; ++c) out_li[obase + (size_t)c * HW] = v[c];

    int ra = ra_grid[gidx];
    if (ra >= 0) {
        const float4* f = (const float4*)(feat2 + ((size_t)b * NR + ra) * C);
        #pragma unroll
        for (int q = 0; q < 8; ++q) {
            float4 t = f[q];
            v[4*q] = t.x; v[4*q+1] = t.y; v[4*q+2] = t.z; v[4*q+3] = t.w;
        }
    } else {
        #pragma unroll
        for (int c = 0; c < C; ++c) v[c] = 0.f;
    }
    #pragma unroll
    for (int c = 0; c < C; ++c) out_ra[obase + (size_t)c * HW] = v[c];
}

extern "C" void kernel_launch(void* const* d_in, const int* in_sizes, int n_in,
                              void* d_out, int out_size, void* d_ws, size_t ws_size,
                              hipStream_t stream) {
    const float*   li_f  = (const float*)d_in[0];
    const int*     li_c  = (const int*)d_in[1];
    const float*   ra_f  = (const float*)d_in[2];
    const int*     ra_c  = (const int*)d_in[3];
    const int*     ra_dy = (const int*)d_in[4];   // jnp bool staged as int32
    const float* ln_li_w = (const float*)d_in[5];
    const float* ln_li_b = (const float*)d_in[6];
    const float* ln_ra_w = (const float*)d_in[7];
    const float* ln_ra_b = (const float*)d_in[8];
    const float* q1w = (const float*)d_in[9],  *q1b = (const float*)d_in[10];
    const float* k1w = (const float*)d_in[11], *k1b = (const float*)d_in[12];
    const float* v1w = (const float*)d_in[13], *v1b = (const float*)d_in[14];
    const float* q2w = (const float*)d_in[15], *q2b = (const float*)d_in[16];
    const float* k2w = (const float*)d_in[17], *k2b = (const float*)d_in[18];
    const float* v2w = (const float*)d_in[19], *v2b = (const float*)d_in[20];
    const float* posw = (const float*)d_in[21], *posb = (const float*)d_in[22];
    const float* a1iw = (const float*)d_in[23], *a1ib = (const float*)d_in[24];
    const float* a1ow = (const float*)d_in[25], *a1ob = (const float*)d_in[26];
    const float* a2iw = (const float*)d_in[27], *a2ib = (const float*)d_in[28];
    const float* a2ow = (const float*)d_in[29], *a2ob = (const float*)d_in[30];

    // ---- workspace carve-up (256B aligned); grids+rdy contiguous for one memset ----
    char* ws = (char*)d_ws;
    size_t off = 0;
    auto carve = [&](size_t bytes) { void* p = ws + off; off += (bytes + 255) & ~(size_t)255; return p; };
    int*     li_grid  = (int*)carve((size_t)B * HW * 4);
    int*     ra_grid  = (int*)carve((size_t)B * HW * 4);
    uint8_t* rdy_grid = (uint8_t*)carve((size_t)B * HW);   // 0xFF = not dy, 0 = dy
    size_t   init_bytes = off;                             // everything above inits to 0xFF
    float*   cb    = (float*)carve((size_t)CB_TOT * 4);
    float*   qp1   = (float*)carve((size_t)B * NL * C * 4);
    float*   kp1   = (float*)carve((size_t)B * NR * C * 4);
    float*   vp1   = (float*)carve((size_t)B * NR * C * 4);
    float*   qp2   = (float*)carve((size_t)B * NR * C * 4);
    float*   kp2   = (float*)carve((size_t)B * NL * C * 4);
    float*   vp2   = (float*)carve((size_t)B * NL * C * 4);
    float*   feat1 = (float*)carve((size_t)B * NL * C * 4);
    float*   feat2 = (float*)carve((size_t)B * NR * C * 4);
    (void)ws_size; (void)n_in; (void)in_sizes; (void)out_size;

    float* out_li = (float*)d_out;
    float* out_ra = out_li + (size_t)B * C * HW;

    // one memset: grids to -1, rdy_grid to 0xFF
    hipMemsetAsync(li_grid, 0xFF, init_bytes, stream);

    // A: grids + rdy + constants
    setup_k<<<dim3(GBL + 7, B), dim3(256), 0, stream>>>(
        li_c, ra_c, ra_dy, li_grid, ra_grid, rdy_grid,
        a1iw, a1ib, a2iw, a2ib, q1w, q1b, k1w, k1b, v1w, v1b,
        q2w, q2b, k2w, k2b, v2w, v2b, posw, posb, cb);

    // B: LN + projections, both modalities
    ln_proj_k<<<dim3(LB + RB, B), dim3(256), 0, stream>>>(
        li_f, ra_f, ln_li_w, ln_li_b, ln_ra_w, ln_ra_b, cb,
        qp1, kp2, vp2, qp2, kp1, vp1);

    // C: attention, both branches (branch-1 computes dy inline)
    attn_k<<<dim3(LB + RB, B), dim3(256), 0, stream>>>(
        qp1, kp1, vp1, qp2, kp2, vp2, li_c, ra_c, li_grid, ra_grid, rdy_grid, cb,
        a1ow, a1ob, a2ow, a2ob, feat1, feat2);

    // D: densify both canvases with coalesced writes
    canvas_k<<<dim3((HW + 255) / 256, B), dim3(256), 0, stream>>>(
        li_grid, ra_grid, feat1, feat2, out_li, out_ra);
}